// Round 2
// baseline (567.136 us; speedup 1.0000x reference)
//
#include <hip/hip_runtime.h>
#include <hip/hip_bf16.h>

typedef float f32x4 __attribute__((ext_vector_type(4)));
typedef short s16x8 __attribute__((ext_vector_type(8)));

#define NB   256
#define NU   512
#define ND0  512
#define ND1  1024
#define WROW (ND0 * ND1)   // elements per u-row of w

__device__ __forceinline__ unsigned int f2bf_pk(float a, float b) {
  __hip_bfloat16 ha = __float2bfloat16(a);
  __hip_bfloat16 hb = __float2bfloat16(b);
  unsigned short ua, ub;
  __builtin_memcpy(&ua, &ha, 2);
  __builtin_memcpy(&ub, &hb, 2);
  return (unsigned int)ua | ((unsigned int)ub << 16);
}

// CK-style barrier: enforces LDS ordering but does NOT drain vmcnt,
// so register-prefetch global loads stay in flight across it.
__device__ __forceinline__ void block_sync_lds() {
  asm volatile("s_waitcnt lgkmcnt(0)" ::: "memory");
  __builtin_amdgcn_s_barrier();
}

// Seed out[b,u] = bias[u]; main kernel atomically accumulates on top.
__global__ __launch_bounds__(256) void init_out(const float* __restrict__ bias,
                                                float* __restrict__ out) {
  int idx = blockIdx.x * 256 + threadIdx.x;   // 512 blocks -> 131072 = 256*512
  out[idx] = bias[idx & (NU - 1)];
}

// out(256x512) = Z(256x524288) @ W^T, Z[b, i*1024+j] = x[b,i]*y[b,j].
// Grid: 512 blocks = 4 u-tiles (BN=128) x 128 K-chunks (4 i0's x full j each).
// Block: 512 threads, 8 waves (2m x 4n); per-wave 8 m-frags x 2 n-frags.
//
// R2 change vs the proven 310us baseline (ONLY change, register-neutral):
// the 64 K-steps are manually 2x-unrolled so wvA/wvB alternate prefetch
// roles. This removes the loop-bottom `wv = wvn` register copy, whose
// implied s_waitcnt on the just-issued prefetch (only ~MFMA+barrier in
// flight) exposed ~1k cycles of DRAM latency per iteration. Now the W
// pack waits on loads that have had a FULL iteration in flight. Body
// ordering and A-synth group structure (v[4] transient) are IDENTICAL
// to the baseline to keep peak register pressure unchanged.
__global__ __launch_bounds__(512, 4) void bilinear_kern(
    const float* __restrict__ x, const float* __restrict__ y,
    const float* __restrict__ w, float* __restrict__ out) {
  __shared__ char Alds[32768];   // 256 rows x 128B (64 bf16), XOR-swizzled
  __shared__ char Wlds[16384];   // 128 rows x 128B (64 bf16), XOR-swizzled

  const int t    = threadIdx.x;
  const int lane = t & 63;
  const int l15  = lane & 15;
  const int lk   = lane >> 4;          // 0..3
  const int wid  = t >> 6;             // 0..7
  const int wm   = wid >> 2;           // 0..1  (m-group: rows wm*128)
  const int wn   = wid & 3;            // 0..3  (n-group: cols wn*32)

  const int nt    = blockIdx.x & 3;    // u-tile
  const int ic    = blockIdx.x >> 2;   // K-chunk: i0 in [ic*4, ic*4+4)
  const int ucol0 = nt * 128 + wn * 32;

  f32x4 acc[8][2];
#pragma unroll
  for (int mf = 0; mf < 8; ++mf)
#pragma unroll
    for (int nf = 0; nf < 2; ++nf)
#pragma unroll
      for (int r = 0; r < 4; ++r) acc[mf][nf][r] = 0.0f;

  // --- A staging map: thread covers rows ar+32p (p=0..7), floats l15*4..+4 ---
  const int ar   = t >> 4;                        // 0..31
  const int aswz = (ar & 7) << 4;                 // (row&7) invariant under +32p
  const int awr  = ar * 128 + ((l15 * 8) ^ aswz); // +p*4096
  const float* yb = y + (size_t)ar * ND1 + l15 * 4;

  // --- W staging map: thread covers rows wrb+4q (q=0..3), floats l15*4..+4 ---
  const int wrb = wid * 16 + lk;                  // 0..127 (wid*16+lk<128)
  const float* wq = w + (size_t)(nt * 128 + wrb) * WROW + l15 * 4;

  // frag-read swizzle: frag rows are l15 mod 8 in both tiles
  const int afswz = (l15 & 7) << 4;

  // ---- prologue: prefetch tile 0's W and the first x column ----
  f32x4 wvA[4], wvB[4];
  {
    const float* p0 = wq + (size_t)(ic * 4) * ND1;
#pragma unroll
    for (int q = 0; q < 4; ++q)
      wvA[q] = *(const f32x4*)(p0 + (size_t)q * 4 * WROW);
  }
  float xv[8];
#pragma unroll
  for (int p = 0; p < 8; ++p)
    xv[p] = x[(size_t)(ar + 32 * p) * ND0 + ic * 4];

#define BODY(IT, WCUR, WNXT)                                                  \
  {                                                                           \
    const int j0 = ((IT) & 15) * 64;                                          \
    block_sync_lds(); /* barrier1: previous tiles fully consumed */           \
    /* ---- A-tile synth: SY[b,jj] = bf16(x[b,i0]*y[b,j0+jj]) ---- */         \
    _Pragma("unroll")                                                         \
    for (int g = 0; g < 2; ++g) {                                             \
      f32x4 v[4];                                                             \
      _Pragma("unroll")                                                       \
      for (int pp = 0; pp < 4; ++pp)                                          \
        v[pp] = *(const f32x4*)(yb + (size_t)(g * 4 + pp) * 32 * ND1 + j0);   \
      _Pragma("unroll")                                                       \
      for (int pp = 0; pp < 4; ++pp) {                                        \
        const int p = g * 4 + pp;                                             \
        unsigned long long pk =                                               \
            (unsigned long long)f2bf_pk(xv[p] * v[pp][0], xv[p] * v[pp][1]) | \
            ((unsigned long long)f2bf_pk(xv[p] * v[pp][2], xv[p] * v[pp][3])  \
             << 32);                                                          \
        *(unsigned long long*)(Alds + awr + p * 4096) = pk;                   \
      }                                                                       \
    }                                                                         \
    /* ---- W-tile pack: regs (a full iteration in flight) -> LDS ---- */     \
    _Pragma("unroll")                                                         \
    for (int q = 0; q < 4; ++q) {                                             \
      const int row  = wrb + 4 * q;                                           \
      const int byte = row * 128 + ((l15 * 8) ^ ((row & 7) << 4));            \
      unsigned long long pk =                                                 \
          (unsigned long long)f2bf_pk(WCUR[q][0], WCUR[q][1]) |               \
          ((unsigned long long)f2bf_pk(WCUR[q][2], WCUR[q][3]) << 32);        \
      *(unsigned long long*)(Wlds + byte) = pk;                               \
    }                                                                         \
    /* ---- prefetch tile IT+1 (in flight across barrier2 + MFMA + */         \
    /* barrier1 + next A-synth; retired at next pack) ---- */                 \
    if ((IT) < 63) {                                                          \
      const int tn = (IT) + 1;                                                \
      const int ii = ic * 4 + (tn >> 4);                                      \
      const int jn = (tn & 15) * 64;                                          \
      const float* pn = wq + (size_t)ii * ND1 + jn;                           \
      _Pragma("unroll")                                                       \
      for (int q = 0; q < 4; ++q)                                             \
        WNXT[q] = *(const f32x4*)(pn + (size_t)q * 4 * WROW);                 \
      if (((IT) & 15) == 15) {                                                \
        _Pragma("unroll")                                                     \
        for (int pp = 0; pp < 8; ++pp)                                        \
          xv[pp] = x[(size_t)(ar + 32 * pp) * ND0 + ii];                      \
      }                                                                       \
    }                                                                         \
    block_sync_lds(); /* barrier2: tiles visible */                           \
    /* ---- MFMA over BK=64 (two k-steps of 32) ---- */                       \
    _Pragma("unroll")                                                         \
    for (int ks = 0; ks < 2; ++ks) {                                          \
      const int kcol = ks * 64;                                               \
      s16x8 bfr[2];                                                           \
      _Pragma("unroll")                                                       \
      for (int nf = 0; nf < 2; ++nf) {                                        \
        const int row = wn * 32 + nf * 16 + l15;                              \
        bfr[nf] = *(const s16x8*)(Wlds + row * 128 + ((kcol + lk * 16) ^ afswz)); \
      }                                                                       \
      _Pragma("unroll")                                                       \
      for (int mf = 0; mf < 8; ++mf) {                                        \
        const int row = wm * 128 + mf * 16 + l15;                             \
        s16x8 af = *(const s16x8*)(Alds + row * 128 + ((kcol + lk * 16) ^ afswz)); \
        acc[mf][0] = __builtin_amdgcn_mfma_f32_16x16x32_bf16(af, bfr[0], acc[mf][0], 0, 0, 0); \
        acc[mf][1] = __builtin_amdgcn_mfma_f32_16x16x32_bf16(af, bfr[1], acc[mf][1], 0, 0, 0); \
      }                                                                       \
    }                                                                         \
  }

  // 64 K-steps, manually 2x-unrolled so wvA/wvB alternate roles:
  // no register copy, no forced wait on a just-issued prefetch.
  for (int ot = 0; ot < 32; ++ot) {
    BODY(2 * ot,     wvA, wvB)
    BODY(2 * ot + 1, wvB, wvA)
  }
#undef BODY

  // ---- epilogue: atomic accumulate partial tile into out ----
  // C/D layout: col = lane&15, row = (lane>>4)*4 + reg
#pragma unroll
  for (int mf = 0; mf < 8; ++mf) {
    const int grow = wm * 128 + mf * 16 + lk * 4;
#pragma unroll
    for (int nf = 0; nf < 2; ++nf) {
      const int gcol = ucol0 + nf * 16 + l15;
#pragma unroll
      for (int r = 0; r < 4; ++r) {
        atomicAdd(out + (size_t)(grow + r) * NU + gcol, acc[mf][nf][r]);
      }
    }
  }
}

extern "C" void kernel_launch(void* const* d_in, const int* in_sizes, int n_in,
                              void* d_out, int out_size, void* d_ws, size_t ws_size,
                              hipStream_t stream) {
  const float* x    = (const float*)d_in[0];
  const float* y    = (const float*)d_in[1];
  const float* w    = (const float*)d_in[2];
  const float* bias = (const float*)d_in[3];
  float* out = (float*)d_out;

  init_out<<<512, 256, 0, stream>>>(bias, out);
  bilinear_kern<<<512, 512, 0, stream>>>(x, y, w, out);
}

// Round 3
// 297.642 us; speedup vs baseline: 1.9054x; 1.9054x over previous
//
#include <hip/hip_runtime.h>
#include <hip/hip_bf16.h>

typedef float f32x4 __attribute__((ext_vector_type(4)));
typedef short s16x8 __attribute__((ext_vector_type(8)));

#define NB   256
#define NU   512
#define ND0  512
#define ND1  1024
#define WROW (ND0 * ND1)   // elements per u-row of w

__device__ __forceinline__ unsigned int f2bf_pk(float a, float b) {
  __hip_bfloat16 ha = __float2bfloat16(a);
  __hip_bfloat16 hb = __float2bfloat16(b);
  unsigned short ua, ub;
  __builtin_memcpy(&ua, &ha, 2);
  __builtin_memcpy(&ub, &hb, 2);
  return (unsigned int)ua | ((unsigned int)ub << 16);
}

// CK-style barrier: enforces LDS ordering but does NOT drain vmcnt,
// so register-prefetch global loads stay in flight across it.
__device__ __forceinline__ void block_sync_lds() {
  asm volatile("s_waitcnt lgkmcnt(0)" ::: "memory");
  __builtin_amdgcn_s_barrier();
}

// Seed out[b,u] = bias[u]; main kernel atomically accumulates on top.
__global__ __launch_bounds__(256) void init_out(const float* __restrict__ bias,
                                                float* __restrict__ out) {
  int idx = blockIdx.x * 256 + threadIdx.x;   // 512 blocks -> 131072 = 256*512
  out[idx] = bias[idx & (NU - 1)];
}

// out(256x512) = Z(256x524288) @ W^T, Z[b, i*1024+j] = x[b,i]*y[b,j].
// Grid: 512 blocks = 4 u-tiles (BN=128) x 128 K-chunks (4 i0's x full j each).
// Block: 512 threads, 8 waves (2m x 4n); per-wave 8 m-frags x 2 n-frags.
// Pipeline (depth-1 register prefetch): W loads for tile t+1 issued before
// barrier2 of tile t; they wait only at W-pack(t+1), so HBM stays busy
// through MFMA + barriers + A-synth.
//
// R3 (ONLY change vs the 310us baseline): W loads are NONTEMPORAL.
// W is read exactly once (zero reuse), but at ~3.5 TB/s it flushes the
// 4MiB/XCD L2 every few us, evicting the y working set (~1MB) that
// A-synth re-reads 2GB-worth across the kernel. nt (evict-first) keeps
// y L2-resident. Structure and register pressure are untouched: R1/R2
// showed the main loop sits at the 128-VGPR cliff (launch_bounds(512,4))
// and ANY structural edit tips it into scratch spills (~1.8x).
__global__ __launch_bounds__(512, 4) void bilinear_kern(
    const float* __restrict__ x, const float* __restrict__ y,
    const float* __restrict__ w, float* __restrict__ out) {
  __shared__ char Alds[32768];   // 256 rows x 128B (64 bf16), XOR-swizzled
  __shared__ char Wlds[16384];   // 128 rows x 128B (64 bf16), XOR-swizzled

  const int t    = threadIdx.x;
  const int lane = t & 63;
  const int l15  = lane & 15;
  const int lk   = lane >> 4;          // 0..3
  const int wid  = t >> 6;             // 0..7
  const int wm   = wid >> 2;           // 0..1  (m-group: rows wm*128)
  const int wn   = wid & 3;            // 0..3  (n-group: cols wn*32)

  const int nt    = blockIdx.x & 3;    // u-tile
  const int ic    = blockIdx.x >> 2;   // K-chunk: i0 in [ic*4, ic*4+4)
  const int ucol0 = nt * 128 + wn * 32;

  f32x4 acc[8][2];
#pragma unroll
  for (int mf = 0; mf < 8; ++mf)
#pragma unroll
    for (int nf = 0; nf < 2; ++nf)
#pragma unroll
      for (int r = 0; r < 4; ++r) acc[mf][nf][r] = 0.0f;

  // --- A staging map: thread covers rows ar+32p (p=0..7), floats l15*4..+4 ---
  const int ar   = t >> 4;                        // 0..31
  const int aswz = (ar & 7) << 4;                 // (row&7) invariant under +32p
  const int awr  = ar * 128 + ((l15 * 8) ^ aswz); // +p*4096
  const float* yb = y + (size_t)ar * ND1 + l15 * 4;

  // --- W staging map: thread covers rows wrb+4q (q=0..3), floats l15*4..+4 ---
  const int wrb = wid * 16 + lk;                  // 0..127 (wid*16+lk<128)
  const float* wq = w + (size_t)(nt * 128 + wrb) * WROW + l15 * 4;

  // frag-read swizzle: frag rows are l15 mod 8 in both tiles
  const int afswz = (l15 & 7) << 4;

  // ---- prologue: prefetch tile 0's W and the first x column ----
  f32x4 wv[4], wvn[4];
  {
    const float* p0 = wq + (size_t)(ic * 4) * ND1;
#pragma unroll
    for (int q = 0; q < 4; ++q)
      wv[q] = __builtin_nontemporal_load((const f32x4*)(p0 + (size_t)q * 4 * WROW));
  }
  float xv[8];
#pragma unroll
  for (int p = 0; p < 8; ++p)
    xv[p] = x[(size_t)(ar + 32 * p) * ND0 + ic * 4];

  for (int it = 0; it < 64; ++it) {
    const int j0 = (it & 15) * 64;

    block_sync_lds();   // barrier1: previous tiles fully consumed

    // ---- A-tile synth: SY[b,jj] = bf16(x[b,i0]*y[b,j0+jj]) ----
#pragma unroll
    for (int g = 0; g < 2; ++g) {
      f32x4 v[4];
#pragma unroll
      for (int pp = 0; pp < 4; ++pp)
        v[pp] = *(const f32x4*)(yb + (size_t)(g * 4 + pp) * 32 * ND1 + j0);
#pragma unroll
      for (int pp = 0; pp < 4; ++pp) {
        const int p = g * 4 + pp;
        unsigned long long pk =
            (unsigned long long)f2bf_pk(xv[p] * v[pp][0], xv[p] * v[pp][1]) |
            ((unsigned long long)f2bf_pk(xv[p] * v[pp][2], xv[p] * v[pp][3]) << 32);
        *(unsigned long long*)(Alds + awr + p * 4096) = pk;
      }
    }

    // ---- W-tile pack: fp32 regs -> bf16 LDS (swizzled); waits on wv here ----
#pragma unroll
    for (int q = 0; q < 4; ++q) {
      const int row  = wrb + 4 * q;
      const int byte = row * 128 + ((l15 * 8) ^ ((row & 7) << 4));
      unsigned long long pk =
          (unsigned long long)f2bf_pk(wv[q][0], wv[q][1]) |
          ((unsigned long long)f2bf_pk(wv[q][2], wv[q][3]) << 32);
      *(unsigned long long*)(Wlds + byte) = pk;
    }

    // ---- prefetch tile it+1 (stays in flight across barrier2 + MFMA) ----
    if (it < 63) {
      const int tn = it + 1;
      const int ii = ic * 4 + (tn >> 4);
      const int jn = (tn & 15) * 64;
      const float* pn = wq + (size_t)ii * ND1 + jn;
#pragma unroll
      for (int q = 0; q < 4; ++q)
        wvn[q] = __builtin_nontemporal_load((const f32x4*)(pn + (size_t)q * 4 * WROW));
      if ((it & 15) == 15) {
#pragma unroll
        for (int pp = 0; pp < 8; ++pp)
          xv[pp] = x[(size_t)(ar + 32 * pp) * ND0 + ii];
      }
    }

    block_sync_lds();   // barrier2: tiles visible

    // ---- MFMA over BK=64 (two k-steps of 32) ----
#pragma unroll
    for (int ks = 0; ks < 2; ++ks) {
      const int kcol = ks * 64;
      s16x8 bf[2];
#pragma unroll
      for (int nf = 0; nf < 2; ++nf) {
        const int row = wn * 32 + nf * 16 + l15;
        bf[nf] = *(const s16x8*)(Wlds + row * 128 + ((kcol + lk * 16) ^ afswz));
      }
#pragma unroll
      for (int mf = 0; mf < 8; ++mf) {
        const int row = wm * 128 + mf * 16 + l15;
        s16x8 af = *(const s16x8*)(Alds + row * 128 + ((kcol + lk * 16) ^ afswz));
        acc[mf][0] = __builtin_amdgcn_mfma_f32_16x16x32_bf16(af, bf[0], acc[mf][0], 0, 0, 0);
        acc[mf][1] = __builtin_amdgcn_mfma_f32_16x16x32_bf16(af, bf[1], acc[mf][1], 0, 0, 0);
      }
    }

#pragma unroll
    for (int q = 0; q < 4; ++q) wv[q] = wvn[q];
  }

  // ---- epilogue: atomic accumulate partial tile into out ----
  // C/D layout: col = lane&15, row = (lane>>4)*4 + reg
#pragma unroll
  for (int mf = 0; mf < 8; ++mf) {
    const int grow = wm * 128 + mf * 16 + lk * 4;
#pragma unroll
    for (int nf = 0; nf < 2; ++nf) {
      const int gcol = ucol0 + nf * 16 + l15;
#pragma unroll
      for (int r = 0; r < 4; ++r) {
        atomicAdd(out + (size_t)(grow + r) * NU + gcol, acc[mf][nf][r]);
      }
    }
  }
}

extern "C" void kernel_launch(void* const* d_in, const int* in_sizes, int n_in,
                              void* d_out, int out_size, void* d_ws, size_t ws_size,
                              hipStream_t stream) {
  const float* x    = (const float*)d_in[0];
  const float* y    = (const float*)d_in[1];
  const float* w    = (const float*)d_in[2];
  const float* bias = (const float*)d_in[3];
  float* out = (float*)d_out;

  init_out<<<512, 256, 0, stream>>>(bias, out);
  bilinear_kern<<<512, 512, 0, stream>>>(x, y, w, out);
}